// Round 1
// baseline (380.906 us; speedup 1.0000x reference)
//
#include <hip/hip_runtime.h>

#define BB 128
#define DD 8732
#define MM 32
#define CC 21

constexpr int K1_PR  = 8;                               // priors per thread
constexpr int K1_CH  = 256 * K1_PR;                     // 2048 priors per block
constexpr int K1_NCH = (DD + K1_CH - 1) / K1_CH;        // 5 chunks
constexpr int K2_CELLS = 256;
constexpr int K2_NBLK  = (DD + K2_CELLS - 1) / K2_CELLS; // 35
constexpr int K2B_PER  = (DD + 255) / 256;               // 35 keys per thread

// ---- workspace layout (bytes) ----
constexpr size_t WS_DPG    = 0;                          // B*M u64 atomicMax keys
constexpr size_t WS_NPOS   = 32768;                      // B i32
constexpr size_t WS_NPT    = 33280;                      // i32 total positives
constexpr size_t WS_CONF   = 33284;                      // f32 conf accumulator
constexpr size_t WS_LOC    = 33288;                      // f32 loc accumulator
constexpr size_t WS_DONE   = 33292;                      // u32 done counter
constexpr size_t WS_ZERO_BYTES = 33296;                  // memset region
constexpr size_t WS_PACKED = 40960;                      // B*D u32 (lab<<8|bm)
constexpr size_t WS_CENEG  = WS_PACKED + (size_t)BB * DD * 4; // B*D f32

__device__ __forceinline__ float wave_sum_f(float v) {
#pragma unroll
  for (int o = 32; o > 0; o >>= 1) v += __shfl_xor(v, o, 64);
  return v;
}
__device__ __forceinline__ int wave_sum_i(int v) {
#pragma unroll
  for (int o = 32; o > 0; o >>= 1) v += __shfl_xor(v, o, 64);
  return v;
}

// ---------------- K1: matching ----------------
__global__ __launch_bounds__(256) void k1_match(
    const float* __restrict__ gt_boxes, const int* __restrict__ gt_labels,
    const float* __restrict__ dboxes,
    unsigned int* __restrict__ packed, unsigned long long* __restrict__ dpg) {
  __shared__ float s_gx1[MM], s_gy1[MM], s_gx2[MM], s_gy2[MM], s_ga[MM];
  __shared__ int s_gl[MM];
  __shared__ unsigned long long s_pm[MM * 4];

  const int b = blockIdx.y;
  const int tid = threadIdx.x;
  if (tid < MM) {
    const float* g = gt_boxes + ((size_t)b * MM + tid) * 4;
    const float x1 = g[0], y1 = g[1], x2 = g[2], y2 = g[3];
    s_gx1[tid] = x1; s_gy1[tid] = y1; s_gx2[tid] = x2; s_gy2[tid] = y2;
    s_ga[tid] = __fmul_rn(__fsub_rn(x2, x1), __fsub_rn(y2, y1));
    s_gl[tid] = gt_labels[b * MM + tid];
  }
  __syncthreads();

  float px1[K1_PR], py1[K1_PR], px2[K1_PR], py2[K1_PR], pa[K1_PR];
  int dd[K1_PR];
  const int dbase = blockIdx.x * K1_CH + tid;
#pragma unroll
  for (int i = 0; i < K1_PR; ++i) {
    const int d = dbase + i * 256;
    if (d < DD) {
      const float4 p = *(const float4*)(dboxes + (size_t)d * 4);
      const float hw = __fmul_rn(p.z, 0.5f), hh = __fmul_rn(p.w, 0.5f);
      px1[i] = __fsub_rn(p.x, hw); py1[i] = __fsub_rn(p.y, hh);
      px2[i] = __fadd_rn(p.x, hw); py2[i] = __fadd_rn(p.y, hh);
      pa[i] = __fmul_rn(__fsub_rn(px2[i], px1[i]), __fsub_rn(py2[i], py1[i]));
      dd[i] = d;
    } else {  // pad: iou=0, can never win ties (huge d)
      px1[i] = 3e9f; py1[i] = 3e9f; px2[i] = 3e9f; py2[i] = 3e9f; pa[i] = 1.0f;
      dd[i] = 0x7FFFFFFF;
    }
  }

  float vb[K1_PR]; int mb[K1_PR];
#pragma unroll
  for (int i = 0; i < K1_PR; ++i) { vb[i] = -1.0f; mb[i] = 0; }

  const int lane = tid & 63, wid = tid >> 6;
  for (int m = 0; m < MM; ++m) {
    const float gx1 = s_gx1[m], gy1 = s_gy1[m], gx2 = s_gx2[m], gy2 = s_gy2[m];
    const float ga = s_ga[m];
    float mv = -1.0f; int md = 0x7FFFFFFF;
#pragma unroll
    for (int i = 0; i < K1_PR; ++i) {
      // exact (non-contracted) f32 to match numpy bit-for-bit
      const float w = fmaxf(0.0f, __fsub_rn(fminf(gx2, px2[i]), fmaxf(gx1, px1[i])));
      const float h = fmaxf(0.0f, __fsub_rn(fminf(gy2, py2[i]), fmaxf(gy1, py1[i])));
      const float inter = __fmul_rn(w, h);
      const float den = __fsub_rn(__fadd_rn(ga, pa[i]), inter);
      const float val = __fdiv_rn(inter, den);
      if (val > vb[i]) { vb[i] = val; mb[i] = m; }   // strict >: first m wins
      if (val > mv) { mv = val; md = dd[i]; }        // d ascending: first d wins
    }
    unsigned long long key =
        (((unsigned long long)__float_as_uint(mv)) << 32) |
        (unsigned long long)(0xFFFFFFFFu - (unsigned)md);
#pragma unroll
    for (int o = 32; o > 0; o >>= 1) {
      const unsigned long long other = __shfl_xor(key, o, 64);
      if (other > key) key = other;
    }
    if (lane == 0) s_pm[m * 4 + wid] = key;
  }
  __syncthreads();
  if (tid < MM) {
    unsigned long long k0 = s_pm[tid * 4 + 0];
    if (s_pm[tid * 4 + 1] > k0) k0 = s_pm[tid * 4 + 1];
    if (s_pm[tid * 4 + 2] > k0) k0 = s_pm[tid * 4 + 2];
    if (s_pm[tid * 4 + 3] > k0) k0 = s_pm[tid * 4 + 3];
    atomicMax(&dpg[b * MM + tid], k0);
  }
#pragma unroll
  for (int i = 0; i < K1_PR; ++i) {
    if (dd[i] < DD) {
      const int lab = (vb[i] < 0.5f) ? 0 : s_gl[mb[i]];
      packed[(size_t)b * DD + dd[i]] = ((unsigned)lab << 8) | (unsigned)mb[i];
    }
  }
}

// ---------------- K2a: CE + loc loss + n_pos ----------------
__global__ __launch_bounds__(256) void k2a_ce(
    const float* __restrict__ loc_pred, const float* __restrict__ cls_pred,
    const float* __restrict__ gt_boxes, const int* __restrict__ gt_labels,
    const float* __restrict__ dboxes, const unsigned int* __restrict__ packed,
    const unsigned long long* __restrict__ dpg, float* __restrict__ ce_neg,
    int* __restrict__ npos, int* __restrict__ npos_total,
    float* __restrict__ conf_acc, float* __restrict__ loc_acc) {
  __shared__ float s_cls[K2_CELLS * CC];
  __shared__ int s_dstar[MM], s_lab[MM];
  __shared__ float s_gt[MM][4];
  __shared__ float s_rf[4], s_rl[4];
  __shared__ int s_ri[4];

  const int b = blockIdx.y;
  const int d0 = blockIdx.x * K2_CELLS;
  const int tid = threadIdx.x;
  const int ncell = min(K2_CELLS, DD - d0);
  const int nflt = ncell * CC;
  const float* srcf = cls_pred + ((size_t)b * DD + d0) * CC;  // 16B-aligned
  const int nv4 = nflt >> 2;
  for (int i = tid; i < nv4; i += 256)
    ((float4*)s_cls)[i] = ((const float4*)srcf)[i];
  for (int i = (nv4 << 2) + tid; i < nflt; i += 256) s_cls[i] = srcf[i];

  if (tid < MM) {
    s_dstar[tid] = (int)(0xFFFFFFFFu - (unsigned)(dpg[b * MM + tid] & 0xFFFFFFFFull));
    s_lab[tid] = gt_labels[b * MM + tid];
    const float4 g = *(const float4*)(gt_boxes + ((size_t)b * MM + tid) * 4);
    s_gt[tid][0] = g.x; s_gt[tid][1] = g.y; s_gt[tid][2] = g.z; s_gt[tid][3] = g.w;
  }
  __syncthreads();

  float ce_pos = 0.0f, sl1 = 0.0f; int posc = 0;
  if (tid < ncell) {
    const int d = d0 + tid;
    const unsigned p = packed[(size_t)b * DD + d];
    int bm = (int)(p & 255u), lab = (int)(p >> 8);
#pragma unroll
    for (int m = 0; m < MM; ++m)  // force-match override, ascending m = last wins
      if (s_dstar[m] == d) { bm = m; lab = s_lab[m]; }
    const float* x = &s_cls[tid * CC];
    float mx = x[0];
#pragma unroll
    for (int c = 1; c < CC; ++c) mx = fmaxf(mx, x[c]);
    float se = 0.0f;
#pragma unroll
    for (int c = 0; c < CC; ++c) se = __fadd_rn(se, __expf(__fsub_rn(x[c], mx)));
    const float ce = __fsub_rn(__fadd_rn(mx, __logf(se)), x[lab]);
    const bool pos = lab > 0;
    ce_neg[(size_t)b * DD + d] = pos ? -1.0f : ce;
    if (pos) {
      posc = 1; ce_pos = ce;
      const float4 lp = *(const float4*)(loc_pred + ((size_t)b * DD + d) * 4);
      const float4 pr = *(const float4*)(dboxes + (size_t)d * 4);  // cx cy w h
      const float gx1 = s_gt[bm][0], gy1 = s_gt[bm][1];
      const float gx2 = s_gt[bm][2], gy2 = s_gt[bm][3];
      const float gcx = __fmul_rn(__fadd_rn(gx1, gx2), 0.5f);
      const float gcy = __fmul_rn(__fadd_rn(gy1, gy2), 0.5f);
      const float gw = __fsub_rn(gx2, gx1), gh = __fsub_rn(gy2, gy1);
      const float t0 = __fdiv_rn(__fsub_rn(gcx, pr.x), __fdiv_rn(pr.z, 10.0f));
      const float t1 = __fdiv_rn(__fsub_rn(gcy, pr.y), __fdiv_rn(pr.w, 10.0f));
      const float t2 = __fmul_rn(__logf(__fdiv_rn(gw, pr.z)), 5.0f);
      const float t3 = __fmul_rn(__logf(__fdiv_rn(gh, pr.w)), 5.0f);
      float dv, ad;
      dv = __fsub_rn(lp.x, t0); ad = fabsf(dv);
      sl1 += (ad < 1.0f) ? __fmul_rn(0.5f, __fmul_rn(dv, dv)) : __fsub_rn(ad, 0.5f);
      dv = __fsub_rn(lp.y, t1); ad = fabsf(dv);
      sl1 += (ad < 1.0f) ? __fmul_rn(0.5f, __fmul_rn(dv, dv)) : __fsub_rn(ad, 0.5f);
      dv = __fsub_rn(lp.z, t2); ad = fabsf(dv);
      sl1 += (ad < 1.0f) ? __fmul_rn(0.5f, __fmul_rn(dv, dv)) : __fsub_rn(ad, 0.5f);
      dv = __fsub_rn(lp.w, t3); ad = fabsf(dv);
      sl1 += (ad < 1.0f) ? __fmul_rn(0.5f, __fmul_rn(dv, dv)) : __fsub_rn(ad, 0.5f);
    }
  }
  const float cs = wave_sum_f(ce_pos);
  const float ls = wave_sum_f(sl1);
  const int ps = wave_sum_i(posc);
  const int lane = tid & 63, wid = tid >> 6;
  if (lane == 0) { s_rf[wid] = cs; s_rl[wid] = ls; s_ri[wid] = ps; }
  __syncthreads();
  if (tid == 0) {
    const float c = s_rf[0] + s_rf[1] + s_rf[2] + s_rf[3];
    const float l = s_rl[0] + s_rl[1] + s_rl[2] + s_rl[3];
    const int p = s_ri[0] + s_ri[1] + s_ri[2] + s_ri[3];
    if (p) { atomicAdd(&npos[b], p); atomicAdd(npos_total, p); }
    atomicAdd(conf_acc, c);
    atomicAdd(loc_acc, l);
  }
}

// ---------------- K2b: per-row top-k negatives + final reduce ----------------
__global__ __launch_bounds__(256) void k2b_topk(
    const float* __restrict__ ce_neg, const int* __restrict__ npos,
    const int* __restrict__ npos_total, float* __restrict__ conf_acc,
    float* __restrict__ loc_acc, unsigned int* __restrict__ done,
    float* __restrict__ out) {
  __shared__ int s_ri[4];
  __shared__ float s_rf[4];
  const int b = blockIdx.x;
  const int tid = threadIdx.x;
  const int lane = tid & 63, wid = tid >> 6;
  const int np = npos[b];
  const int k = min(3 * np, DD - np);

  unsigned key[K2B_PER];
#pragma unroll
  for (int i = 0; i < K2B_PER; ++i) {
    const int d = tid + i * 256;
    if (d < DD) {
      const unsigned u = __float_as_uint(ce_neg[(size_t)b * DD + d]);
      key[i] = (u & 0x80000000u) ? ~u : (u | 0x80000000u);  // sortable key
    } else key[i] = 0u;
  }

  if (k > 0) {
    unsigned T = 0u;
    for (int bit = 31; bit >= 0; --bit) {
      const unsigned cand = T | (1u << bit);
      int c = 0;
#pragma unroll
      for (int i = 0; i < K2B_PER; ++i) c += (key[i] >= cand) ? 1 : 0;
      c = wave_sum_i(c);
      if (lane == 0) s_ri[wid] = c;
      __syncthreads();
      const int total = s_ri[0] + s_ri[1] + s_ri[2] + s_ri[3];
      __syncthreads();
      if (total >= k) T = cand;
    }
    int c = 0; float s = 0.0f;
#pragma unroll
    for (int i = 0; i < K2B_PER; ++i) {
      if (key[i] > T) { c += 1; s += __uint_as_float(key[i] ^ 0x80000000u); }
    }
    c = wave_sum_i(c); s = wave_sum_f(s);
    if (lane == 0) { s_ri[wid] = c; s_rf[wid] = s; }
    __syncthreads();
    if (tid == 0) {
      const int cg = s_ri[0] + s_ri[1] + s_ri[2] + s_ri[3];
      const float sg = s_rf[0] + s_rf[1] + s_rf[2] + s_rf[3];
      const float vT = __uint_as_float(T ^ 0x80000000u);
      atomicAdd(conf_acc, sg + (float)(k - cg) * vT);
    }
  }
  if (tid == 0) {
    __threadfence();
    const unsigned old = atomicAdd(done, 1u);
    if (old == BB - 1) {  // last row: finalize
      const float conf = atomicAdd(conf_acc, 0.0f);
      const float loc = atomicAdd(loc_acc, 0.0f);
      const int npt = *npos_total;
      const float nt = (float)((npt > 0) ? npt : 1);
      out[0] = __fdiv_rn(__fadd_rn(conf, loc), nt);
    }
  }
}

extern "C" void kernel_launch(void* const* d_in, const int* in_sizes, int n_in,
                              void* d_out, int out_size, void* d_ws, size_t ws_size,
                              hipStream_t stream) {
  const float* loc_pred = (const float*)d_in[0];
  const float* cls_pred = (const float*)d_in[1];
  const float* gt_boxes = (const float*)d_in[2];
  const int* gt_labels = (const int*)d_in[3];
  const float* dboxes = (const float*)d_in[4];

  char* ws = (char*)d_ws;
  unsigned long long* dpg = (unsigned long long*)(ws + WS_DPG);
  int* npos = (int*)(ws + WS_NPOS);
  int* npos_total = (int*)(ws + WS_NPT);
  float* conf_acc = (float*)(ws + WS_CONF);
  float* loc_acc = (float*)(ws + WS_LOC);
  unsigned int* done = (unsigned int*)(ws + WS_DONE);
  unsigned int* packed = (unsigned int*)(ws + WS_PACKED);
  float* ce_neg = (float*)(ws + WS_CENEG);

  hipMemsetAsync(ws, 0, WS_ZERO_BYTES, stream);

  k1_match<<<dim3(K1_NCH, BB), 256, 0, stream>>>(gt_boxes, gt_labels, dboxes,
                                                 packed, dpg);
  k2a_ce<<<dim3(K2_NBLK, BB), 256, 0, stream>>>(loc_pred, cls_pred, gt_boxes,
                                                gt_labels, dboxes, packed, dpg,
                                                ce_neg, npos, npos_total,
                                                conf_acc, loc_acc);
  k2b_topk<<<BB, 256, 0, stream>>>(ce_neg, npos, npos_total, conf_acc, loc_acc,
                                   done, (float*)d_out);
}

// Round 2
// 241.880 us; speedup vs baseline: 1.5748x; 1.5748x over previous
//
#include <hip/hip_runtime.h>

#define BB 128
#define DD 8732
#define MM 32
#define CC 21

constexpr int K1_PR  = 8;                               // priors per thread
constexpr int K1_CH  = 256 * K1_PR;                     // 2048 priors per block
constexpr int K1_NCH = (DD + K1_CH - 1) / K1_CH;        // 5 chunks
constexpr int K2_CELLS = 256;
constexpr int K2_NBLK  = (DD + K2_CELLS - 1) / K2_CELLS; // 35
constexpr int K2B_PER  = (DD + 255) / 256;               // 35 keys per thread

// ---- workspace layout (bytes) ----
// Atomic targets are spread across cache lines: per-row 64-B accumulator
// slots, and gsum/gnpos/done each on a private 128-B line. Round-1 post-
// mortem: conf/loc/npos_total on ONE line ate 13440 serialized atomics
// (~175 us) — that was the whole k2a stall.
constexpr size_t WS_DPG    = 0;                          // B*M u64 atomicMax keys (32768 B)
constexpr size_t WS_ROW    = 32768;                      // B rows * 64 B: [0]=conf f32, [1]=loc f32, [2]=npos i32
constexpr int    ROW_STRIDE = 16;                        // floats per row slot (64 B)
constexpr size_t WS_GSUM   = 40960;                      // f32, own line
constexpr size_t WS_GNPOS  = 41088;                      // i32, own line
constexpr size_t WS_DONE   = 41216;                      // u32, own line
constexpr size_t WS_ZERO_BYTES = 41344;                  // memset region
constexpr size_t WS_PACKED = 41472;                      // B*D u32 (lab<<8|bm)
constexpr size_t WS_CENEG  = WS_PACKED + (size_t)BB * DD * 4; // B*D f32

__device__ __forceinline__ float wave_sum_f(float v) {
#pragma unroll
  for (int o = 32; o > 0; o >>= 1) v += __shfl_xor(v, o, 64);
  return v;
}
__device__ __forceinline__ int wave_sum_i(int v) {
#pragma unroll
  for (int o = 32; o > 0; o >>= 1) v += __shfl_xor(v, o, 64);
  return v;
}

// ---------------- K1: matching ----------------
__global__ __launch_bounds__(256) void k1_match(
    const float* __restrict__ gt_boxes, const int* __restrict__ gt_labels,
    const float* __restrict__ dboxes,
    unsigned int* __restrict__ packed, unsigned long long* __restrict__ dpg) {
  __shared__ float s_gx1[MM], s_gy1[MM], s_gx2[MM], s_gy2[MM], s_ga[MM];
  __shared__ int s_gl[MM];
  __shared__ unsigned long long s_pm[MM * 4];

  const int b = blockIdx.y;
  const int tid = threadIdx.x;
  if (tid < MM) {
    const float* g = gt_boxes + ((size_t)b * MM + tid) * 4;
    const float x1 = g[0], y1 = g[1], x2 = g[2], y2 = g[3];
    s_gx1[tid] = x1; s_gy1[tid] = y1; s_gx2[tid] = x2; s_gy2[tid] = y2;
    s_ga[tid] = __fmul_rn(__fsub_rn(x2, x1), __fsub_rn(y2, y1));
    s_gl[tid] = gt_labels[b * MM + tid];
  }
  __syncthreads();

  float px1[K1_PR], py1[K1_PR], px2[K1_PR], py2[K1_PR], pa[K1_PR];
  int dd[K1_PR];
  const int dbase = blockIdx.x * K1_CH + tid;
#pragma unroll
  for (int i = 0; i < K1_PR; ++i) {
    const int d = dbase + i * 256;
    if (d < DD) {
      const float4 p = *(const float4*)(dboxes + (size_t)d * 4);
      const float hw = __fmul_rn(p.z, 0.5f), hh = __fmul_rn(p.w, 0.5f);
      px1[i] = __fsub_rn(p.x, hw); py1[i] = __fsub_rn(p.y, hh);
      px2[i] = __fadd_rn(p.x, hw); py2[i] = __fadd_rn(p.y, hh);
      pa[i] = __fmul_rn(__fsub_rn(px2[i], px1[i]), __fsub_rn(py2[i], py1[i]));
      dd[i] = d;
    } else {  // pad: iou=0, can never win ties (huge d)
      px1[i] = 3e9f; py1[i] = 3e9f; px2[i] = 3e9f; py2[i] = 3e9f; pa[i] = 1.0f;
      dd[i] = 0x7FFFFFFF;
    }
  }

  float vb[K1_PR]; int mb[K1_PR];
#pragma unroll
  for (int i = 0; i < K1_PR; ++i) { vb[i] = -1.0f; mb[i] = 0; }

  const int lane = tid & 63, wid = tid >> 6;
  for (int m = 0; m < MM; ++m) {
    const float gx1 = s_gx1[m], gy1 = s_gy1[m], gx2 = s_gx2[m], gy2 = s_gy2[m];
    const float ga = s_ga[m];
    float mv = -1.0f; int md = 0x7FFFFFFF;
#pragma unroll
    for (int i = 0; i < K1_PR; ++i) {
      // exact (non-contracted) f32 to match numpy bit-for-bit
      const float w = fmaxf(0.0f, __fsub_rn(fminf(gx2, px2[i]), fmaxf(gx1, px1[i])));
      const float h = fmaxf(0.0f, __fsub_rn(fminf(gy2, py2[i]), fmaxf(gy1, py1[i])));
      const float inter = __fmul_rn(w, h);
      const float den = __fsub_rn(__fadd_rn(ga, pa[i]), inter);
      const float val = __fdiv_rn(inter, den);
      if (val > vb[i]) { vb[i] = val; mb[i] = m; }   // strict >: first m wins
      if (val > mv) { mv = val; md = dd[i]; }        // d ascending: first d wins
    }
    unsigned long long key =
        (((unsigned long long)__float_as_uint(mv)) << 32) |
        (unsigned long long)(0xFFFFFFFFu - (unsigned)md);
#pragma unroll
    for (int o = 32; o > 0; o >>= 1) {
      const unsigned long long other = __shfl_xor(key, o, 64);
      if (other > key) key = other;
    }
    if (lane == 0) s_pm[m * 4 + wid] = key;
  }
  __syncthreads();
  if (tid < MM) {
    unsigned long long k0 = s_pm[tid * 4 + 0];
    if (s_pm[tid * 4 + 1] > k0) k0 = s_pm[tid * 4 + 1];
    if (s_pm[tid * 4 + 2] > k0) k0 = s_pm[tid * 4 + 2];
    if (s_pm[tid * 4 + 3] > k0) k0 = s_pm[tid * 4 + 3];
    atomicMax(&dpg[b * MM + tid], k0);
  }
#pragma unroll
  for (int i = 0; i < K1_PR; ++i) {
    if (dd[i] < DD) {
      const int lab = (vb[i] < 0.5f) ? 0 : s_gl[mb[i]];
      packed[(size_t)b * DD + dd[i]] = ((unsigned)lab << 8) | (unsigned)mb[i];
    }
  }
}

// ---------------- K2a: CE + loc loss + n_pos (per-row accumulators) -------
__global__ __launch_bounds__(256) void k2a_ce(
    const float* __restrict__ loc_pred, const float* __restrict__ cls_pred,
    const float* __restrict__ gt_boxes, const int* __restrict__ gt_labels,
    const float* __restrict__ dboxes, const unsigned int* __restrict__ packed,
    const unsigned long long* __restrict__ dpg, float* __restrict__ ce_neg,
    float* __restrict__ rowacc) {
  __shared__ float s_cls[K2_CELLS * CC];
  __shared__ int s_dstar[MM], s_lab[MM];
  __shared__ float s_gt[MM][4];
  __shared__ float s_rf[4], s_rl[4];
  __shared__ int s_ri[4];

  const int b = blockIdx.y;
  const int d0 = blockIdx.x * K2_CELLS;
  const int tid = threadIdx.x;
  const int ncell = min(K2_CELLS, DD - d0);
  const int nflt = ncell * CC;
  const float* srcf = cls_pred + ((size_t)b * DD + d0) * CC;  // 16B-aligned
  const int nv4 = nflt >> 2;
  for (int i = tid; i < nv4; i += 256)
    ((float4*)s_cls)[i] = ((const float4*)srcf)[i];
  for (int i = (nv4 << 2) + tid; i < nflt; i += 256) s_cls[i] = srcf[i];

  if (tid < MM) {
    s_dstar[tid] = (int)(0xFFFFFFFFu - (unsigned)(dpg[b * MM + tid] & 0xFFFFFFFFull));
    s_lab[tid] = gt_labels[b * MM + tid];
    const float4 g = *(const float4*)(gt_boxes + ((size_t)b * MM + tid) * 4);
    s_gt[tid][0] = g.x; s_gt[tid][1] = g.y; s_gt[tid][2] = g.z; s_gt[tid][3] = g.w;
  }
  __syncthreads();

  float ce_pos = 0.0f, sl1 = 0.0f; int posc = 0;
  if (tid < ncell) {
    const int d = d0 + tid;
    const unsigned p = packed[(size_t)b * DD + d];
    int bm = (int)(p & 255u), lab = (int)(p >> 8);
#pragma unroll
    for (int m = 0; m < MM; ++m)  // force-match override, ascending m = last wins
      if (s_dstar[m] == d) { bm = m; lab = s_lab[m]; }
    const float* x = &s_cls[tid * CC];
    float mx = x[0];
#pragma unroll
    for (int c = 1; c < CC; ++c) mx = fmaxf(mx, x[c]);
    float se = 0.0f;
#pragma unroll
    for (int c = 0; c < CC; ++c) se = __fadd_rn(se, __expf(__fsub_rn(x[c], mx)));
    const float ce = __fsub_rn(__fadd_rn(mx, __logf(se)), x[lab]);
    const bool pos = lab > 0;
    ce_neg[(size_t)b * DD + d] = pos ? -1.0f : ce;
    if (pos) {
      posc = 1; ce_pos = ce;
      const float4 lp = *(const float4*)(loc_pred + ((size_t)b * DD + d) * 4);
      const float4 pr = *(const float4*)(dboxes + (size_t)d * 4);  // cx cy w h
      const float gx1 = s_gt[bm][0], gy1 = s_gt[bm][1];
      const float gx2 = s_gt[bm][2], gy2 = s_gt[bm][3];
      const float gcx = __fmul_rn(__fadd_rn(gx1, gx2), 0.5f);
      const float gcy = __fmul_rn(__fadd_rn(gy1, gy2), 0.5f);
      const float gw = __fsub_rn(gx2, gx1), gh = __fsub_rn(gy2, gy1);
      const float t0 = __fdiv_rn(__fsub_rn(gcx, pr.x), __fdiv_rn(pr.z, 10.0f));
      const float t1 = __fdiv_rn(__fsub_rn(gcy, pr.y), __fdiv_rn(pr.w, 10.0f));
      const float t2 = __fmul_rn(__logf(__fdiv_rn(gw, pr.z)), 5.0f);
      const float t3 = __fmul_rn(__logf(__fdiv_rn(gh, pr.w)), 5.0f);
      float dv, ad;
      dv = __fsub_rn(lp.x, t0); ad = fabsf(dv);
      sl1 += (ad < 1.0f) ? __fmul_rn(0.5f, __fmul_rn(dv, dv)) : __fsub_rn(ad, 0.5f);
      dv = __fsub_rn(lp.y, t1); ad = fabsf(dv);
      sl1 += (ad < 1.0f) ? __fmul_rn(0.5f, __fmul_rn(dv, dv)) : __fsub_rn(ad, 0.5f);
      dv = __fsub_rn(lp.z, t2); ad = fabsf(dv);
      sl1 += (ad < 1.0f) ? __fmul_rn(0.5f, __fmul_rn(dv, dv)) : __fsub_rn(ad, 0.5f);
      dv = __fsub_rn(lp.w, t3); ad = fabsf(dv);
      sl1 += (ad < 1.0f) ? __fmul_rn(0.5f, __fmul_rn(dv, dv)) : __fsub_rn(ad, 0.5f);
    }
  }
  const float cs = wave_sum_f(ce_pos);
  const float ls = wave_sum_f(sl1);
  const int ps = wave_sum_i(posc);
  const int lane = tid & 63, wid = tid >> 6;
  if (lane == 0) { s_rf[wid] = cs; s_rl[wid] = ls; s_ri[wid] = ps; }
  __syncthreads();
  if (tid == 0) {
    const float c = s_rf[0] + s_rf[1] + s_rf[2] + s_rf[3];
    const float l = s_rl[0] + s_rl[1] + s_rl[2] + s_rl[3];
    const int p = s_ri[0] + s_ri[1] + s_ri[2] + s_ri[3];
    float* row = rowacc + b * ROW_STRIDE;   // 64-B private slot for row b
    atomicAdd(&row[0], c);
    atomicAdd(&row[1], l);
    if (p) atomicAdd((int*)&row[2], p);
  }
}

// ---------------- K2b: per-row top-k negatives + final reduce ----------------
__global__ __launch_bounds__(256) void k2b_topk(
    const float* __restrict__ ce_neg, const float* __restrict__ rowacc,
    float* __restrict__ gsum, int* __restrict__ gnpos,
    unsigned int* __restrict__ done, float* __restrict__ out) {
  __shared__ int s_ri[4];
  __shared__ float s_rf[4];
  const int b = blockIdx.x;
  const int tid = threadIdx.x;
  const int lane = tid & 63, wid = tid >> 6;
  const float* row = rowacc + b * ROW_STRIDE;
  const int np = ((const int*)row)[2];
  const int k = min(3 * np, DD - np);

  unsigned key[K2B_PER];
#pragma unroll
  for (int i = 0; i < K2B_PER; ++i) {
    const int d = tid + i * 256;
    if (d < DD) {
      const unsigned u = __float_as_uint(ce_neg[(size_t)b * DD + d]);
      key[i] = (u & 0x80000000u) ? ~u : (u | 0x80000000u);  // sortable key
    } else key[i] = 0u;
  }

  float topk_sum = 0.0f;
  if (k > 0) {
    unsigned T = 0u;
    for (int bit = 31; bit >= 0; --bit) {
      const unsigned cand = T | (1u << bit);
      int c = 0;
#pragma unroll
      for (int i = 0; i < K2B_PER; ++i) c += (key[i] >= cand) ? 1 : 0;
      c = wave_sum_i(c);
      if (lane == 0) s_ri[wid] = c;
      __syncthreads();
      const int total = s_ri[0] + s_ri[1] + s_ri[2] + s_ri[3];
      __syncthreads();
      if (total >= k) T = cand;
    }
    int c = 0; float s = 0.0f;
#pragma unroll
    for (int i = 0; i < K2B_PER; ++i) {
      if (key[i] > T) { c += 1; s += __uint_as_float(key[i] ^ 0x80000000u); }
    }
    c = wave_sum_i(c); s = wave_sum_f(s);
    if (lane == 0) { s_ri[wid] = c; s_rf[wid] = s; }
    __syncthreads();
    if (tid == 0) {
      const int cg = s_ri[0] + s_ri[1] + s_ri[2] + s_ri[3];
      const float sg = s_rf[0] + s_rf[1] + s_rf[2] + s_rf[3];
      const float vT = __uint_as_float(T ^ 0x80000000u);
      topk_sum = sg + (float)(k - cg) * vT;
    }
  }
  if (tid == 0) {
    // one atomic per row into dedicated lines (128-way total, not 13k-way)
    atomicAdd(gsum, row[0] + row[1] + topk_sum);
    atomicAdd(gnpos, np);
    __threadfence();
    const unsigned old = atomicAdd(done, 1u);
    if (old == BB - 1) {  // last row: finalize
      const float total = atomicAdd(gsum, 0.0f);
      const int npt = atomicAdd(gnpos, 0);
      const float nt = (float)((npt > 0) ? npt : 1);
      out[0] = __fdiv_rn(total, nt);
    }
  }
}

extern "C" void kernel_launch(void* const* d_in, const int* in_sizes, int n_in,
                              void* d_out, int out_size, void* d_ws, size_t ws_size,
                              hipStream_t stream) {
  const float* loc_pred = (const float*)d_in[0];
  const float* cls_pred = (const float*)d_in[1];
  const float* gt_boxes = (const float*)d_in[2];
  const int* gt_labels = (const int*)d_in[3];
  const float* dboxes = (const float*)d_in[4];

  char* ws = (char*)d_ws;
  unsigned long long* dpg = (unsigned long long*)(ws + WS_DPG);
  float* rowacc = (float*)(ws + WS_ROW);
  float* gsum = (float*)(ws + WS_GSUM);
  int* gnpos = (int*)(ws + WS_GNPOS);
  unsigned int* done = (unsigned int*)(ws + WS_DONE);
  unsigned int* packed = (unsigned int*)(ws + WS_PACKED);
  float* ce_neg = (float*)(ws + WS_CENEG);

  hipMemsetAsync(ws, 0, WS_ZERO_BYTES, stream);

  k1_match<<<dim3(K1_NCH, BB), 256, 0, stream>>>(gt_boxes, gt_labels, dboxes,
                                                 packed, dpg);
  k2a_ce<<<dim3(K2_NBLK, BB), 256, 0, stream>>>(loc_pred, cls_pred, gt_boxes,
                                                gt_labels, dboxes, packed, dpg,
                                                ce_neg, rowacc);
  k2b_topk<<<BB, 256, 0, stream>>>(ce_neg, rowacc, gsum, gnpos, done,
                                   (float*)d_out);
}

// Round 3
// 231.554 us; speedup vs baseline: 1.6450x; 1.0446x over previous
//
#include <hip/hip_runtime.h>

#define BB 128
#define DD 8732
#define MM 32
#define CC 21

constexpr int K1_PR  = 4;                               // priors per thread (R2: 8->4 for occupancy)
constexpr int K1_CH  = 256 * K1_PR;                     // 1024 priors per block
constexpr int K1_NCH = (DD + K1_CH - 1) / K1_CH;        // 9 chunks -> 1152 blocks
constexpr int K2_CELLS = 256;
constexpr int K2_NBLK  = (DD + K2_CELLS - 1) / K2_CELLS; // 35
constexpr int K2B_T    = 1024;                           // k2b block size (R2: 256->1024)
constexpr int K2B_PER  = (DD + K2B_T - 1) / K2B_T;       // 9 keys per thread
constexpr int K2B_W    = K2B_T / 64;                     // 16 waves

// ---- workspace layout (bytes) ----
// Atomic targets spread across cache lines (R1 post-mortem: one shared line
// for conf/loc/npos cost ~175 us of serialized atomics).
constexpr size_t WS_DPG    = 0;                          // B*M u64 atomicMax keys (32768 B)
constexpr size_t WS_ROW    = 32768;                      // B rows * 64 B: [0]=conf f32, [1]=loc f32, [2]=npos i32
constexpr int    ROW_STRIDE = 16;                        // floats per row slot (64 B)
constexpr size_t WS_GSUM   = 40960;                      // f32, own line
constexpr size_t WS_GNPOS  = 41088;                      // i32, own line
constexpr size_t WS_DONE   = 41216;                      // u32, own line
constexpr size_t WS_ZERO_BYTES = 41344;                  // memset region
constexpr size_t WS_PACKED = 41472;                      // B*D u32 (lab<<8|bm)
constexpr size_t WS_CENEG  = WS_PACKED + (size_t)BB * DD * 4; // B*D f32

__device__ __forceinline__ float wave_sum_f(float v) {
#pragma unroll
  for (int o = 32; o > 0; o >>= 1) v += __shfl_xor(v, o, 64);
  return v;
}
__device__ __forceinline__ int wave_sum_i(int v) {
#pragma unroll
  for (int o = 32; o > 0; o >>= 1) v += __shfl_xor(v, o, 64);
  return v;
}

// ---------------- K1: matching ----------------
__global__ __launch_bounds__(256) void k1_match(
    const float* __restrict__ gt_boxes, const int* __restrict__ gt_labels,
    const float* __restrict__ dboxes,
    unsigned int* __restrict__ packed, unsigned long long* __restrict__ dpg) {
  __shared__ float s_gx1[MM], s_gy1[MM], s_gx2[MM], s_gy2[MM], s_ga[MM];
  __shared__ int s_gl[MM];
  __shared__ unsigned long long s_pm[MM * 4];

  const int b = blockIdx.y;
  const int tid = threadIdx.x;
  if (tid < MM) {
    const float* g = gt_boxes + ((size_t)b * MM + tid) * 4;
    const float x1 = g[0], y1 = g[1], x2 = g[2], y2 = g[3];
    s_gx1[tid] = x1; s_gy1[tid] = y1; s_gx2[tid] = x2; s_gy2[tid] = y2;
    s_ga[tid] = __fmul_rn(__fsub_rn(x2, x1), __fsub_rn(y2, y1));
    s_gl[tid] = gt_labels[b * MM + tid];
  }
  __syncthreads();

  float px1[K1_PR], py1[K1_PR], px2[K1_PR], py2[K1_PR], pa[K1_PR];
  int dd[K1_PR];
  const int dbase = blockIdx.x * K1_CH + tid;
#pragma unroll
  for (int i = 0; i < K1_PR; ++i) {
    const int d = dbase + i * 256;
    if (d < DD) {
      const float4 p = *(const float4*)(dboxes + (size_t)d * 4);
      const float hw = __fmul_rn(p.z, 0.5f), hh = __fmul_rn(p.w, 0.5f);
      px1[i] = __fsub_rn(p.x, hw); py1[i] = __fsub_rn(p.y, hh);
      px2[i] = __fadd_rn(p.x, hw); py2[i] = __fadd_rn(p.y, hh);
      pa[i] = __fmul_rn(__fsub_rn(px2[i], px1[i]), __fsub_rn(py2[i], py1[i]));
      dd[i] = d;
    } else {  // pad: iou=0, can never win ties (huge d)
      px1[i] = 3e9f; py1[i] = 3e9f; px2[i] = 3e9f; py2[i] = 3e9f; pa[i] = 1.0f;
      dd[i] = 0x7FFFFFFF;
    }
  }

  float vb[K1_PR]; int mb[K1_PR];
#pragma unroll
  for (int i = 0; i < K1_PR; ++i) { vb[i] = -1.0f; mb[i] = 0; }

  const int lane = tid & 63, wid = tid >> 6;
  for (int m = 0; m < MM; ++m) {
    const float gx1 = s_gx1[m], gy1 = s_gy1[m], gx2 = s_gx2[m], gy2 = s_gy2[m];
    const float ga = s_ga[m];
    float mv = -1.0f; int md = 0x7FFFFFFF;
#pragma unroll
    for (int i = 0; i < K1_PR; ++i) {
      // exact (non-contracted) f32 to match numpy bit-for-bit
      const float w = fmaxf(0.0f, __fsub_rn(fminf(gx2, px2[i]), fmaxf(gx1, px1[i])));
      const float h = fmaxf(0.0f, __fsub_rn(fminf(gy2, py2[i]), fmaxf(gy1, py1[i])));
      const float inter = __fmul_rn(w, h);
      const float den = __fsub_rn(__fadd_rn(ga, pa[i]), inter);
      const float val = __fdiv_rn(inter, den);
      if (val > vb[i]) { vb[i] = val; mb[i] = m; }   // strict >: first m wins
      if (val > mv) { mv = val; md = dd[i]; }        // d ascending: first d wins
    }
    unsigned long long key =
        (((unsigned long long)__float_as_uint(mv)) << 32) |
        (unsigned long long)(0xFFFFFFFFu - (unsigned)md);
#pragma unroll
    for (int o = 32; o > 0; o >>= 1) {
      const unsigned long long other = __shfl_xor(key, o, 64);
      if (other > key) key = other;
    }
    if (lane == 0) s_pm[m * 4 + wid] = key;
  }
  __syncthreads();
  if (tid < MM) {
    unsigned long long k0 = s_pm[tid * 4 + 0];
    if (s_pm[tid * 4 + 1] > k0) k0 = s_pm[tid * 4 + 1];
    if (s_pm[tid * 4 + 2] > k0) k0 = s_pm[tid * 4 + 2];
    if (s_pm[tid * 4 + 3] > k0) k0 = s_pm[tid * 4 + 3];
    atomicMax(&dpg[b * MM + tid], k0);
  }
#pragma unroll
  for (int i = 0; i < K1_PR; ++i) {
    if (dd[i] < DD) {
      const int lab = (vb[i] < 0.5f) ? 0 : s_gl[mb[i]];
      packed[(size_t)b * DD + dd[i]] = ((unsigned)lab << 8) | (unsigned)mb[i];
    }
  }
}

// ---------------- K2a: CE + loc loss + n_pos (per-row accumulators) -------
__global__ __launch_bounds__(256) void k2a_ce(
    const float* __restrict__ loc_pred, const float* __restrict__ cls_pred,
    const float* __restrict__ gt_boxes, const int* __restrict__ gt_labels,
    const float* __restrict__ dboxes, const unsigned int* __restrict__ packed,
    const unsigned long long* __restrict__ dpg, float* __restrict__ ce_neg,
    float* __restrict__ rowacc) {
  __shared__ float s_cls[K2_CELLS * CC];
  __shared__ int s_dstar[MM], s_lab[MM];
  __shared__ float s_gt[MM][4];
  __shared__ float s_rf[4], s_rl[4];
  __shared__ int s_ri[4];

  const int b = blockIdx.y;
  const int d0 = blockIdx.x * K2_CELLS;
  const int tid = threadIdx.x;
  const int ncell = min(K2_CELLS, DD - d0);
  const int nflt = ncell * CC;
  const float* srcf = cls_pred + ((size_t)b * DD + d0) * CC;  // 16B-aligned
  const int nv4 = nflt >> 2;
  for (int i = tid; i < nv4; i += 256)
    ((float4*)s_cls)[i] = ((const float4*)srcf)[i];
  for (int i = (nv4 << 2) + tid; i < nflt; i += 256) s_cls[i] = srcf[i];

  if (tid < MM) {
    s_dstar[tid] = (int)(0xFFFFFFFFu - (unsigned)(dpg[b * MM + tid] & 0xFFFFFFFFull));
    s_lab[tid] = gt_labels[b * MM + tid];
    const float4 g = *(const float4*)(gt_boxes + ((size_t)b * MM + tid) * 4);
    s_gt[tid][0] = g.x; s_gt[tid][1] = g.y; s_gt[tid][2] = g.z; s_gt[tid][3] = g.w;
  }
  __syncthreads();

  float ce_pos = 0.0f, sl1 = 0.0f; int posc = 0;
  if (tid < ncell) {
    const int d = d0 + tid;
    const unsigned p = packed[(size_t)b * DD + d];
    int bm = (int)(p & 255u), lab = (int)(p >> 8);
#pragma unroll
    for (int m = 0; m < MM; ++m)  // force-match override, ascending m = last wins
      if (s_dstar[m] == d) { bm = m; lab = s_lab[m]; }
    const float* x = &s_cls[tid * CC];
    float mx = x[0];
#pragma unroll
    for (int c = 1; c < CC; ++c) mx = fmaxf(mx, x[c]);
    float se = 0.0f;
#pragma unroll
    for (int c = 0; c < CC; ++c) se = __fadd_rn(se, __expf(__fsub_rn(x[c], mx)));
    const float ce = __fsub_rn(__fadd_rn(mx, __logf(se)), x[lab]);
    const bool pos = lab > 0;
    ce_neg[(size_t)b * DD + d] = pos ? -1.0f : ce;
    if (pos) {
      posc = 1; ce_pos = ce;
      const float4 lp = *(const float4*)(loc_pred + ((size_t)b * DD + d) * 4);
      const float4 pr = *(const float4*)(dboxes + (size_t)d * 4);  // cx cy w h
      const float gx1 = s_gt[bm][0], gy1 = s_gt[bm][1];
      const float gx2 = s_gt[bm][2], gy2 = s_gt[bm][3];
      const float gcx = __fmul_rn(__fadd_rn(gx1, gx2), 0.5f);
      const float gcy = __fmul_rn(__fadd_rn(gy1, gy2), 0.5f);
      const float gw = __fsub_rn(gx2, gx1), gh = __fsub_rn(gy2, gy1);
      const float t0 = __fdiv_rn(__fsub_rn(gcx, pr.x), __fdiv_rn(pr.z, 10.0f));
      const float t1 = __fdiv_rn(__fsub_rn(gcy, pr.y), __fdiv_rn(pr.w, 10.0f));
      const float t2 = __fmul_rn(__logf(__fdiv_rn(gw, pr.z)), 5.0f);
      const float t3 = __fmul_rn(__logf(__fdiv_rn(gh, pr.w)), 5.0f);
      float dv, ad;
      dv = __fsub_rn(lp.x, t0); ad = fabsf(dv);
      sl1 += (ad < 1.0f) ? __fmul_rn(0.5f, __fmul_rn(dv, dv)) : __fsub_rn(ad, 0.5f);
      dv = __fsub_rn(lp.y, t1); ad = fabsf(dv);
      sl1 += (ad < 1.0f) ? __fmul_rn(0.5f, __fmul_rn(dv, dv)) : __fsub_rn(ad, 0.5f);
      dv = __fsub_rn(lp.z, t2); ad = fabsf(dv);
      sl1 += (ad < 1.0f) ? __fmul_rn(0.5f, __fmul_rn(dv, dv)) : __fsub_rn(ad, 0.5f);
      dv = __fsub_rn(lp.w, t3); ad = fabsf(dv);
      sl1 += (ad < 1.0f) ? __fmul_rn(0.5f, __fmul_rn(dv, dv)) : __fsub_rn(ad, 0.5f);
    }
  }
  const float cs = wave_sum_f(ce_pos);
  const float ls = wave_sum_f(sl1);
  const int ps = wave_sum_i(posc);
  const int lane = tid & 63, wid = tid >> 6;
  if (lane == 0) { s_rf[wid] = cs; s_rl[wid] = ls; s_ri[wid] = ps; }
  __syncthreads();
  if (tid == 0) {
    const float c = s_rf[0] + s_rf[1] + s_rf[2] + s_rf[3];
    const float l = s_rl[0] + s_rl[1] + s_rl[2] + s_rl[3];
    const int p = s_ri[0] + s_ri[1] + s_ri[2] + s_ri[3];
    float* row = rowacc + b * ROW_STRIDE;   // 64-B private slot for row b
    atomicAdd(&row[0], c);
    atomicAdd(&row[1], l);
    if (p) atomicAdd((int*)&row[2], p);
  }
}

// ---------------- K2b: per-row top-k negatives + final reduce ----------------
__global__ __launch_bounds__(K2B_T) void k2b_topk(
    const float* __restrict__ ce_neg, const float* __restrict__ rowacc,
    float* __restrict__ gsum, int* __restrict__ gnpos,
    unsigned int* __restrict__ done, float* __restrict__ out) {
  __shared__ int s_ri[K2B_W];
  __shared__ float s_rf[K2B_W];
  const int b = blockIdx.x;
  const int tid = threadIdx.x;
  const int lane = tid & 63, wid = tid >> 6;
  const float* row = rowacc + b * ROW_STRIDE;
  const int np = ((const int*)row)[2];
  const int k = min(3 * np, DD - np);

  unsigned key[K2B_PER];
#pragma unroll
  for (int i = 0; i < K2B_PER; ++i) {
    const int d = tid + i * K2B_T;
    if (d < DD) {
      const unsigned u = __float_as_uint(ce_neg[(size_t)b * DD + d]);
      key[i] = (u & 0x80000000u) ? ~u : (u | 0x80000000u);  // sortable key
    } else key[i] = 0u;
  }

  float topk_sum = 0.0f;
  if (k > 0) {
    unsigned T = 0u;
    for (int bit = 31; bit >= 0; --bit) {
      const unsigned cand = T | (1u << bit);
      int c = 0;
#pragma unroll
      for (int i = 0; i < K2B_PER; ++i) c += (key[i] >= cand) ? 1 : 0;
      c = wave_sum_i(c);
      if (lane == 0) s_ri[wid] = c;
      __syncthreads();
      int total = 0;
#pragma unroll
      for (int w = 0; w < K2B_W; ++w) total += s_ri[w];
      __syncthreads();
      if (total >= k) T = cand;
    }
    int c = 0; float s = 0.0f;
#pragma unroll
    for (int i = 0; i < K2B_PER; ++i) {
      if (key[i] > T) { c += 1; s += __uint_as_float(key[i] ^ 0x80000000u); }
    }
    c = wave_sum_i(c); s = wave_sum_f(s);
    if (lane == 0) { s_ri[wid] = c; s_rf[wid] = s; }
    __syncthreads();
    if (tid == 0) {
      int cg = 0; float sg = 0.0f;
#pragma unroll
      for (int w = 0; w < K2B_W; ++w) { cg += s_ri[w]; sg += s_rf[w]; }
      const float vT = __uint_as_float(T ^ 0x80000000u);
      topk_sum = sg + (float)(k - cg) * vT;
    }
  }
  if (tid == 0) {
    // one atomic per row into dedicated lines (128-way total, not 13k-way)
    atomicAdd(gsum, row[0] + row[1] + topk_sum);
    atomicAdd(gnpos, np);
    __threadfence();
    const unsigned old = atomicAdd(done, 1u);
    if (old == BB - 1) {  // last row: finalize
      const float total = atomicAdd(gsum, 0.0f);
      const int npt = atomicAdd(gnpos, 0);
      const float nt = (float)((npt > 0) ? npt : 1);
      out[0] = __fdiv_rn(total, nt);
    }
  }
}

extern "C" void kernel_launch(void* const* d_in, const int* in_sizes, int n_in,
                              void* d_out, int out_size, void* d_ws, size_t ws_size,
                              hipStream_t stream) {
  const float* loc_pred = (const float*)d_in[0];
  const float* cls_pred = (const float*)d_in[1];
  const float* gt_boxes = (const float*)d_in[2];
  const int* gt_labels = (const int*)d_in[3];
  const float* dboxes = (const float*)d_in[4];

  char* ws = (char*)d_ws;
  unsigned long long* dpg = (unsigned long long*)(ws + WS_DPG);
  float* rowacc = (float*)(ws + WS_ROW);
  float* gsum = (float*)(ws + WS_GSUM);
  int* gnpos = (int*)(ws + WS_GNPOS);
  unsigned int* done = (unsigned int*)(ws + WS_DONE);
  unsigned int* packed = (unsigned int*)(ws + WS_PACKED);
  float* ce_neg = (float*)(ws + WS_CENEG);

  hipMemsetAsync(ws, 0, WS_ZERO_BYTES, stream);

  k1_match<<<dim3(K1_NCH, BB), 256, 0, stream>>>(gt_boxes, gt_labels, dboxes,
                                                 packed, dpg);
  k2a_ce<<<dim3(K2_NBLK, BB), 256, 0, stream>>>(loc_pred, cls_pred, gt_boxes,
                                                gt_labels, dboxes, packed, dpg,
                                                ce_neg, rowacc);
  k2b_topk<<<BB, K2B_T, 0, stream>>>(ce_neg, rowacc, gsum, gnpos, done,
                                     (float*)d_out);
}